// Round 9
// baseline (475.704 us; speedup 1.0000x reference)
//
#include <hip/hip_runtime.h>
#include <cmath>

typedef unsigned short u16;
typedef __attribute__((ext_vector_type(8))) __bf16 bf16x8;
typedef __attribute__((ext_vector_type(4))) float f32x4;

constexpr int Bb = 2, Tt = 8, Dc = 128, PIX = 4096; // b=2, c=128, 64x64 imgs

__device__ inline u16 f2bf(float f) {
    unsigned u = __builtin_bit_cast(unsigned, f);
    u += 0x7fffu + ((u >> 16) & 1u);
    return (u16)(u >> 16);
}
__device__ inline float bf2f(u16 h) {
    unsigned u = ((unsigned)h) << 16;
    return __builtin_bit_cast(float, u);
}

#define GLOAD16(gp, lp) __builtin_amdgcn_global_load_lds( \
    (const __attribute__((address_space(1))) void*)(const void*)(gp), \
    (__attribute__((address_space(3))) void*)(void*)(lp), 16, 0, 0)

// ---------------------------------------------------------------------------
// bf16 NT MFMA core, BK=64 (r9): stage TWO 32-K chunks per barrier pair into
// 32KB LDS (two 8KB halves per operand), then 2x mfma_chunk. Halves the
// barrier/vmcnt(0)-drain frequency that bounded r8 (MfmaUtil 15% at split-K's
// short K-extents). 32KB -> 5 blocks/CU cap, above our 4-block launches.
// (r6: register pipelines get collapsed by compiler; m132: BK=128/64KB LDS
// regresses occupancy -- BK=64 is the middle point.)
// ---------------------------------------------------------------------------
__device__ inline void mfma_chunk(const u16* lAs, const u16* lBs, int wave, int lane,
                                  f32x4 (&acc)[4][4])
{
    const int wm = (wave >> 1) * 64, wn = (wave & 1) * 64;
    const int fr = lane & 15;
    const int q4 = lane >> 4;                         // wanted global k-quarter
    const int sw = (q4 ^ ((fr >> 1) & 3)) * 8;        // swizzled storage seg
    bf16x8 av[4], bv[4];
#pragma unroll
    for (int i = 0; i < 4; ++i) av[i] = *(const bf16x8*)&lAs[(wm + i * 16 + fr) * 32 + sw];
#pragma unroll
    for (int j = 0; j < 4; ++j) bv[j] = *(const bf16x8*)&lBs[(wn + j * 16 + fr) * 32 + sw];
#pragma unroll
    for (int i = 0; i < 4; ++i)
#pragma unroll
        for (int j = 0; j < 4; ++j)
            acc[i][j] = __builtin_amdgcn_mfma_f32_16x16x32_bf16(av[i], bv[j], acc[i][j], 0, 0, 0);
}

// kChunks = number of 32-K chunks, must be EVEN.
__device__ inline void mfma_nt(const u16* A, int ldkA, const u16* B, int ldkB,
                               int kChunks, int wave, int lane,
                               u16* lAs, u16* lBs, f32x4 (&acc)[4][4])
{
    const int r = lane >> 2;                              // row within 16-group
    const int kq8 = ((lane & 3) ^ ((r >> 1) & 3)) * 8;    // swizzled source seg
    const u16* ga0 = A + (size_t)(wave * 32 + r) * ldkA + kq8;
    const u16* ga1 = ga0 + (size_t)16 * ldkA;
    const u16* gb0 = B + (size_t)(wave * 32 + r) * ldkB + kq8;
    const u16* gb1 = gb0 + (size_t)16 * ldkB;
    for (int kb = 0; kb < kChunks; kb += 2) {
        __syncthreads();                       // WAR: prior pair's ds_reads done
        GLOAD16(ga0 + kb * 32, lAs + wave * 1024);
        GLOAD16(ga1 + kb * 32, lAs + wave * 1024 + 512);
        GLOAD16(gb0 + kb * 32, lBs + wave * 1024);
        GLOAD16(gb1 + kb * 32, lBs + wave * 1024 + 512);
        GLOAD16(ga0 + (kb + 1) * 32, lAs + 4096 + wave * 1024);
        GLOAD16(ga1 + (kb + 1) * 32, lAs + 4096 + wave * 1024 + 512);
        GLOAD16(gb0 + (kb + 1) * 32, lBs + 4096 + wave * 1024);
        GLOAD16(gb1 + (kb + 1) * 32, lBs + 4096 + wave * 1024 + 512);
        __syncthreads();                       // drains vmcnt(0) before barrier
        mfma_chunk(lAs, lBs, wave, lane, acc);
        mfma_chunk(lAs + 4096, lBs + 4096, wave, lane, acc);
    }
}

// ---------------------------------------------------------------------------
// Weight prep: Wqkv[3*128][128] bf16 stacked; WoT[tap][cout][cin] bf16.
// ---------------------------------------------------------------------------
__global__ void k_prep(const float* __restrict__ wq, const float* __restrict__ wk,
                       const float* __restrict__ wv, const float* __restrict__ wo,
                       u16* __restrict__ Wqkv, u16* __restrict__ WoT)
{
    int idx = blockIdx.x * 256 + threadIdx.x;
    if (idx < 49152) {
        const float* w = idx < 16384 ? wq : (idx < 32768 ? wk : wv);
        Wqkv[idx] = f2bf(w[idx & 16383]);
    }
    int j = idx - 49152;
    if (j >= 0 && j < 147456) {
        int tap = j / 16384, rem = j % 16384;  // rem = cout*128+cin
        WoT[j] = f2bf(wo[(size_t)rem * 9 + tap]);
    }
}

// ---------------------------------------------------------------------------
// Xt[n][pix][cin] bf16 from x[n][cin][pix] fp32 (LDS transpose, 64-pix tiles)
// ---------------------------------------------------------------------------
__global__ __launch_bounds__(256) void k_xt(const float* __restrict__ x, u16* __restrict__ Xt)
{
    __shared__ float ls[128 * 65];
    const int n = blockIdx.y, pix0 = blockIdx.x * 64;
#pragma unroll
    for (int rep = 0; rep < 32; ++rep) {
        int idx = rep * 256 + threadIdx.x;
        int cin = idx >> 6, p = idx & 63;
        ls[cin * 65 + p] = x[((size_t)n * Dc + cin) * PIX + pix0 + p];
    }
    __syncthreads();
#pragma unroll
    for (int rep = 0; rep < 32; ++rep) {
        int idx = rep * 256 + threadIdx.x;
        int p = idx >> 7, cin = idx & 127;
        Xt[((size_t)n * PIX + pix0 + p) * Dc + cin] = f2bf(ls[cin * 65 + p]);
    }
}

// ---------------------------------------------------------------------------
// Fused QKV GEMM; Q/K scattered directly into patched layouts (both scales).
// grid (32 pixtiles, 3 mt, 16 imgs) = 1536 blocks.
// ---------------------------------------------------------------------------
__global__ __launch_bounds__(256) void k_qkv_mfma(const u16* __restrict__ Wqkv,
                                                  const u16* __restrict__ Xt,
                                                  const float* __restrict__ bq,
                                                  const float* __restrict__ bk,
                                                  const float* __restrict__ bv,
                                                  u16* __restrict__ Qp0, u16* __restrict__ Kp0,
                                                  u16* __restrict__ Qp1, u16* __restrict__ Kp1,
                                                  u16* __restrict__ v_bf)
{
    __shared__ u16 lAs[8192], lBs[8192];
    const int tid = threadIdx.x, wave = tid >> 6, lane = tid & 63;
    const int mt = blockIdx.y, n = blockIdx.z, px0 = blockIdx.x * 128;
    f32x4 acc[4][4];
#pragma unroll
    for (int i = 0; i < 4; ++i)
#pragma unroll
        for (int j = 0; j < 4; ++j) acc[i][j] = (f32x4){0.f, 0.f, 0.f, 0.f};
    mfma_nt(Wqkv + (size_t)mt * 128 * 128, 128,
            Xt + ((size_t)n * PIX + px0) * 128, 128, 4, wave, lane, lAs, lBs, acc);
    const int wm = (wave >> 1) * 64, wn = (wave & 1) * 64;
    const int rb = (lane >> 4) * 4, cb = lane & 15;
    const int bi = n >> 3, ti = n & 7;
    if (mt < 2) {
        const float* bp = (mt == 0) ? bq : bk;
        u16* d0 = (mt == 0) ? Qp0 : Kp0;
        u16* d1 = (mt == 0) ? Qp1 : Kp1;
#pragma unroll
        for (int i = 0; i < 4; ++i)
#pragma unroll
            for (int reg = 0; reg < 4; ++reg) {
                int c = wm + i * 16 + rb + reg;          // 0..127
                float bias = bp[c];
#pragma unroll
                for (int j = 0; j < 4; ++j) {
                    int pix = px0 + wn + j * 16 + cb;
                    int y = pix >> 6, x = pix & 63;
                    u16 val = f2bf(acc[i][j][reg] + bias);
                    if (c < 64) {                         // scale 0 (ps=4)
                        int l = ti * 256 + (y >> 2) * 16 + (x >> 2);
                        int f = c * 16 + (y & 3) * 4 + (x & 3);
                        d0[((size_t)bi * 2048 + l) * 1024 + f] = val;
                    } else {                              // scale 1 (ps=8)
                        int l = ti * 64 + (y >> 3) * 8 + (x >> 3);
                        int f = (c - 64) * 64 + (y & 7) * 8 + (x & 7);
                        d1[((size_t)bi * 512 + l) * 4096 + f] = val;
                    }
                }
            }
    } else {
#pragma unroll
        for (int i = 0; i < 4; ++i)
#pragma unroll
            for (int reg = 0; reg < 4; ++reg) {
                int c = wm + i * 16 + rb + reg;
                float bias = bv[c];
#pragma unroll
                for (int j = 0; j < 4; ++j) {
                    int pix = px0 + wn + j * 16 + cb;
                    v_bf[((size_t)n * Dc + c) * PIX + pix] = f2bf(acc[i][j][reg] + bias);
                }
            }
    }
}

// ---------------------------------------------------------------------------
// Depthwise 3x3 add into bf16 v_all: block per (c,n), x staged in LDS once.
// grid (128, 16).
// ---------------------------------------------------------------------------
__global__ __launch_bounds__(256) void k_vdw(const float* __restrict__ X,
                                             const float* __restrict__ wvle,
                                             const float* __restrict__ bvle,
                                             u16* __restrict__ v_bf)
{
    __shared__ float ls[4096];
    const int c = blockIdx.x, n = blockIdx.y;
    const int tid = threadIdx.x;
    const float* xp = X + ((size_t)n * Dc + c) * PIX;
#pragma unroll
    for (int r = 0; r < 4; ++r)
        *(float4*)&ls[r * 1024 + tid * 4] = *(const float4*)&xp[r * 1024 + tid * 4];
    __syncthreads();
    float w[9];
#pragma unroll
    for (int t = 0; t < 9; ++t) w[t] = wvle[c * 9 + t];   // uniform -> s_load
    const float bias = bvle[c];
    const int x = tid & 63, y0 = (tid >> 6) * 16;
    const bool xl = (x > 0), xr = (x < 63);
    u16* vp = v_bf + ((size_t)n * Dc + c) * PIX;
#pragma unroll
    for (int r = 0; r < 16; ++r) {
        int y = y0 + r;
        float s = bias;
#pragma unroll
        for (int ky = 0; ky < 3; ++ky) {
            int yy = y + ky - 1;
            if (yy < 0 || yy > 63) continue;              // wave-uniform edges
            const float* row = &ls[yy * 64];
            float m  = row[x];
            float lv = xl ? row[x - 1] : 0.f;
            float rv = xr ? row[x + 1] : 0.f;
            s += w[ky * 3 + 0] * lv + w[ky * 3 + 1] * m + w[ky * 3 + 2] * rv;
        }
        int idx = y * 64 + x;
        vp[idx] = f2bf(bf2f(vp[idx]) + s);
    }
}

// ---------------------------------------------------------------------------
// Depth path, kernel 1: d1[n][c][128][128] = relu(conv(dm, wd1, s2, p1)) bf16.
// ---------------------------------------------------------------------------
__global__ __launch_bounds__(256) void k_d1(const float* __restrict__ dm,
                                            const float* __restrict__ wd1,
                                            const float* __restrict__ bd1,
                                            u16* __restrict__ d1b)
{
    __shared__ float ls[17 * 132];
    const int n = blockIdx.y;
    const int yt = blockIdx.x >> 1, xh = blockIdx.x & 1;
    const int Y0 = yt * 8;
    const int tid = threadIdx.x;
    const float* dmp = dm + (size_t)n * 65536;
    for (int idx = tid; idx < 17 * 132; idx += 256) {
        int row = idx / 132, cl = idx % 132;
        int gr = 2 * Y0 - 1 + row;
        int gc = 128 * xh - 1 + cl;
        float v = 0.f;
        if (gr >= 0 && gr < 256 && gc >= 0 && gc < 256 && cl < 129) v = dmp[gr * 256 + gc];
        ls[idx] = v;
    }
    __syncthreads();
    const int Xl = tid & 63;
    const int Yl0 = tid >> 6;                 // rows Yl0 and Yl0+4
    float in0[9], in1[9];
#pragma unroll
    for (int jy = 0; jy < 3; ++jy)
#pragma unroll
        for (int jx = 0; jx < 3; ++jx) {
            in0[jy * 3 + jx] = ls[(2 * Yl0 + jy) * 132 + 2 * Xl + jx];
            in1[jy * 3 + jx] = ls[(2 * (Yl0 + 4) + jy) * 132 + 2 * Xl + jx];
        }
    const int X = 64 * xh + Xl;
    u16* outbase = d1b + (size_t)n * Dc * 16384 + (size_t)Y0 * 128 + X;
    for (int c = 0; c < 128; ++c) {
        const float* w1 = wd1 + c * 9;        // uniform -> s_load
        float a0 = bd1[c], a1 = a0;
#pragma unroll
        for (int t = 0; t < 9; ++t) { a0 += w1[t] * in0[t]; a1 += w1[t] * in1[t]; }
        u16* ob = outbase + (size_t)c * 16384;
        ob[(size_t)Yl0 * 128]       = f2bf(fmaxf(a0, 0.f));
        ob[(size_t)(Yl0 + 4) * 128] = f2bf(fmaxf(a1, 0.f));
    }
}

// ---------------------------------------------------------------------------
// Depth path, kernel 2: partial conv2 over 16-channel groups.
// ---------------------------------------------------------------------------
__global__ __launch_bounds__(256) void k_d2p(const u16* __restrict__ d1b,
                                             const float* __restrict__ wd2,
                                             float* __restrict__ part)
{
    __shared__ u16 ls[33 * 136];              // payload at cl 8..135, zero at cl 7
    const int yt = blockIdx.x, n = blockIdx.y, cg = blockIdx.z;
    const int tid = threadIdx.x;
    const int y0 = yt * 16;
    if (tid < 33) ls[tid * 136 + 7] = 0;
    const int x = tid & 63;
    const int yl0 = (tid >> 6) * 4;
    float acc[4] = {0.f, 0.f, 0.f, 0.f};
    for (int c = 0; c < 16; ++c) {
        const u16* src = d1b + ((size_t)n * Dc + cg * 16 + c) * 16384;
        __syncthreads();
        for (int idx = tid; idx < 33 * 16; idx += 256) {
            int row = idx >> 4, s = idx & 15;
            int gr = 2 * y0 - 1 + row;
            uint4 v = make_uint4(0, 0, 0, 0);
            if (gr >= 0 && gr < 128) v = *(const uint4*)(src + gr * 128 + s * 8);
            *(uint4*)&ls[row * 136 + 8 + s * 8] = v;
        }
        __syncthreads();
        const float* w2 = wd2 + (cg * 16 + c) * 9;   // uniform -> s_load
        float w[9];
#pragma unroll
        for (int t = 0; t < 9; ++t) w[t] = w2[t];
#pragma unroll
        for (int r = 0; r < 4; ++r) {
            int yl = yl0 + r;
#pragma unroll
            for (int ky = 0; ky < 3; ++ky) {
                const u16* rp = &ls[(2 * yl + ky) * 136 + 2 * x + 7];
                float v0 = bf2f(rp[0]);
                unsigned pr = *(const unsigned*)(rp + 1);
                float v1 = bf2f((u16)(pr & 0xffffu));
                float v2 = bf2f((u16)(pr >> 16));
                acc[r] += w[ky * 3 + 0] * v0 + w[ky * 3 + 1] * v1 + w[ky * 3 + 2] * v2;
            }
        }
    }
    float* pp = part + ((size_t)cg * 16 + n) * PIX;
#pragma unroll
    for (int r = 0; r < 4; ++r)
        pp[(y0 + yl0 + r) * 64 + x] = acc[r];
}

// Depth path, kernel 3: dep = relu(sum_cg part + bd2). grid (256)
__global__ void k_dfin(const float* __restrict__ part, const float* __restrict__ bd2,
                       float* __restrict__ dep)
{
    int idx = blockIdx.x * 256 + threadIdx.x;
    float s = bd2[0];
#pragma unroll
    for (int cg = 0; cg < 8; ++cg) s += part[(size_t)cg * 65536 + idx];
    dep[idx] = fmaxf(s, 0.f);
}

// ---------------------------------------------------------------------------
// Wave-parallel per-token stats (min/max/mask butterfly, exact median rank).
// ---------------------------------------------------------------------------
template<int PS>
__global__ __launch_bounds__(256) void k_stats2(const float* __restrict__ mI,
                                                const float* __restrict__ dep,
                                                float* __restrict__ maskf,
                                                float* __restrict__ smed,
                                                float* __restrict__ smaxA,
                                                float* __restrict__ sminA,
                                                int outn, int L)
{
    constexpr int HW = PS * PS;              // 16 or 64
    constexpr int TPB = 256 / HW;
    const int tok = blockIdx.x * TPB + threadIdx.x / HW;
    const int el  = threadIdx.x % HW;
    if (tok >= Bb * L) return;
    const int bi = tok / L, l = tok % L;
    const int ti = l / (outn * outn); const int rem = l % (outn * outn);
    const int oh = rem / outn, ow = rem % outn;
    const int n = bi * Tt + ti;
    const int py = el / PS, px = el % PS;
    const size_t off = (size_t)n * PIX + (size_t)(oh * PS + py) * 64 + ow * PS + px;
    const float mv = mI[off];
    const float dv = dep[off];
    float msum = mv, vmin = dv, vmax = dv;
#pragma unroll
    for (int o = HW / 2; o > 0; o >>= 1) {
        msum += __shfl_xor(msum, o);
        vmin = fminf(vmin, __shfl_xor(vmin, o));
        vmax = fmaxf(vmax, __shfl_xor(vmax, o));
    }
    const int gbase = (threadIdx.x & 63) & ~(HW - 1);
    int cl = 0, ce = 0;
#pragma unroll
    for (int b2 = 0; b2 < HW; ++b2) {
        float vb = __shfl(dv, gbase + b2);
        cl += (vb < dv);
        ce += (vb == dv);
    }
    constexpr int kk = (HW - 1) / 2;
    if (el == 0) {
        maskf[tok] = (msum / (float)HW > 0.5f) ? 1.f : 0.f;
        smaxA[tok] = 1.f / (1.f + __expf(-vmax));
        sminA[tok] = 1.f / (1.f + __expf(-vmin));
    }
    if (cl <= kk && kk < cl + ce)
        smed[tok] = 1.f / (1.f + __expf(-dv));
}

// V transposed patch: Vt[bi][f][l] bf16. 4 consecutive l per thread.
__global__ void k_patchT(const u16* __restrict__ v_bf, u16* __restrict__ Vt,
                         int ps, int outn, int L, int F, int cbase)
{
    size_t idx = (size_t)blockIdx.x * 256 + threadIdx.x;
    size_t total = (size_t)Bb * F * L / 4;
    if (idx >= total) return;
    int l0 = (int)((idx * 4) % L);
    size_t t2 = (idx * 4) / L;
    int f = (int)(t2 % F);
    int bi = (int)(t2 / F);
    int hw = ps * ps;
    int c = cbase + f / hw, r = f % hw;
    int py = r / ps, px = r % ps;
    int ti = l0 / (outn * outn); int rem = l0 % (outn * outn);
    int oh = rem / outn, ow0 = rem % outn;
    size_t base = ((size_t)(bi * Tt + ti) * Dc + c) * PIX + (oh * ps + py) * 64 + px;
    u16 out4[4];
#pragma unroll
    for (int e = 0; e < 4; ++e) out4[e] = v_bf[base + (size_t)(ow0 + e) * ps];
    *(uint2*)&Vt[((size_t)bi * F + f) * L + l0] = *(uint2*)out4;
}

// ---------------------------------------------------------------------------
// S = scale * Q K^T (LDS MFMA BK=64), bf16 partials.
// grid (L/128, L/128, Bb*ksplit).
// ---------------------------------------------------------------------------
__global__ __launch_bounds__(256) void k_qkT_mfma(const u16* __restrict__ Qp,
                                                  const u16* __restrict__ Kp,
                                                  u16* __restrict__ S,
                                                  int L, int F, int ksplit, float scale)
{
    __shared__ u16 lAs[8192], lBs[8192];
    const int tid = threadIdx.x, wave = tid >> 6, lane = tid & 63;
    const int bi = blockIdx.z / ksplit, ks = blockIdx.z % ksplit;
    const int kf = F / ksplit;
    f32x4 acc[4][4];
#pragma unroll
    for (int i = 0; i < 4; ++i)
#pragma unroll
        for (int j = 0; j < 4; ++j) acc[i][j] = (f32x4){0.f, 0.f, 0.f, 0.f};
    mfma_nt(Qp + (size_t)bi * L * F + (size_t)blockIdx.y * 128 * F + (size_t)ks * kf, F,
            Kp + (size_t)bi * L * F + (size_t)blockIdx.x * 128 * F + (size_t)ks * kf, F,
            kf / 32, wave, lane, lAs, lBs, acc);
    const int wm = (wave >> 1) * 64, wn = (wave & 1) * 64;
    const int rb = (lane >> 4) * 4, cb = lane & 15;
    u16* Cp = S + ((size_t)ks * Bb + bi) * L * L;
#pragma unroll
    for (int i = 0; i < 4; ++i)
#pragma unroll
        for (int reg = 0; reg < 4; ++reg) {
            int gm = blockIdx.y * 128 + wm + i * 16 + rb + reg;
#pragma unroll
            for (int j = 0; j < 4; ++j) {
                int gn = blockIdx.x * 128 + wn + j * 16 + cb;
                Cp[(size_t)gm * L + gn] = f2bf(acc[i][j][reg] * scale);
            }
        }
}

// ---------------------------------------------------------------------------
// 3-head softmax, r9: VECTORIZED -- thread owns NV consecutive columns, so
// bf16 reads are uint2 loads and the P store is one 16B (NV=8) store.
// Sums NSPLIT bf16 partial S buffers in fp32.
// ---------------------------------------------------------------------------
__device__ inline float blockMax(float v, float* sh) {
#pragma unroll
    for (int o = 32; o > 0; o >>= 1) v = fmaxf(v, __shfl_down(v, o));
    __syncthreads();
    if ((threadIdx.x & 63) == 0) sh[threadIdx.x >> 6] = v;
    __syncthreads();
    return fmaxf(fmaxf(sh[0], sh[1]), fmaxf(sh[2], sh[3]));
}
__device__ inline float blockSum(float v, float* sh) {
#pragma unroll
    for (int o = 32; o > 0; o >>= 1) v += __shfl_down(v, o);
    __syncthreads();
    if ((threadIdx.x & 63) == 0) sh[threadIdx.x >> 6] = v;
    __syncthreads();
    return sh[0] + sh[1] + sh[2] + sh[3];
}

template<int NV, int NSPLIT>
__global__ __launch_bounds__(256) void k_softmax(const u16* __restrict__ S,
                                                 u16* __restrict__ Pb,
                                                 const float* __restrict__ maskf,
                                                 const float* __restrict__ smed,
                                                 const float* __restrict__ smaxA,
                                                 const float* __restrict__ sminA,
                                                 int L)
{
    __shared__ float sred[4];
    const int bi = blockIdx.y, q = blockIdx.x;
    const size_t pstr = (size_t)Bb * L * L;
    const u16* row = S + (size_t)bi * L * L + (size_t)q * L;
    u16* prow = Pb + (size_t)bi * L * L + (size_t)q * L;
    const float* mk  = maskf + bi * L;
    const float* s0p = smed  + bi * L;
    const float* s1p = smaxA + bi * L;
    const float* s2p = sminA + bi * L;
    const int tid = threadIdx.x;
    const int k0 = tid * NV;                  // NV consecutive columns per thread
    float a0[NV], a1[NV], a2[NV];
    float m0 = -3.4e38f, m1 = -3.4e38f, m2 = -3.4e38f;
#pragma unroll
    for (int e = 0; e < NV; e += 2) {
        int k = k0 + e;
        unsigned u = *(const unsigned*)&row[k];
        float sva = bf2f((u16)(u & 0xffffu));
        float svb = bf2f((u16)(u >> 16));
#pragma unroll
        for (int s2 = 1; s2 < NSPLIT; ++s2) {
            unsigned w = *(const unsigned*)&row[(size_t)s2 * pstr + k];
            sva += bf2f((u16)(w & 0xffffu));
            svb += bf2f((u16)(w >> 16));
        }
        float sv2[2] = {sva, svb};
#pragma unroll
        for (int c2 = 0; c2 < 2; ++c2) {
            int kc = k + c2;
            bool msk = mk[kc] > 0.5f;
            float sv = sv2[c2];
            float v0 = msk ? -1e9f : sv * s0p[kc];
            float v1 = msk ? -1e9f : sv * s1p[kc];
            float v2 = msk ? -1e9f : sv * s2p[kc];
            a0[e + c2] = v0; a1[e + c2] = v1; a2[e + c2] = v2;
            m0 = fmaxf(m0, v0); m1 = fmaxf(m1, v1); m2 = fmaxf(m2, v2);
        }
    }
    m0 = blockMax(m0, sred); m1 = blockMax(m1, sred); m2 = blockMax(m2, sred);
    float l0 = 0.f, l1 = 0.f, l2 = 0.f;
#pragma unroll
    for (int e = 0; e < NV; ++e) {
        a0[e] = __expf(a0[e] - m0); l0 += a0[e];
        a1[e] = __expf(a1[e] - m1); l1 += a1[e];
        a2[e] = __expf(a2[e] - m2); l2 += a2[e];
    }
    l0 = blockSum(l0, sred); l1 = blockSum(l1, sred); l2 = blockSum(l2, sred);
    float c0 = 1.f / (3.f * l0), c1 = 1.f / (3.f * l1), c2 = 1.f / (3.f * l2);
    u16 outv[NV];
#pragma unroll
    for (int e = 0; e < NV; ++e)
        outv[e] = f2bf(a0[e] * c0 + a1[e] * c1 + a2[e] * c2);
    if (NV == 8)      *(uint4*)&prow[k0] = *(uint4*)outv;
    else if (NV == 2) *(unsigned*)&prow[k0] = *(unsigned*)outv;
    else {
#pragma unroll
        for (int e = 0; e < NV; ++e) prow[k0 + e] = outv[e];
    }
}

// ---------------------------------------------------------------------------
// Y = P @ V (LDS MFMA BK=64, split-K=4 -> 1024 blocks). bf16 partials.
// ---------------------------------------------------------------------------
__global__ __launch_bounds__(256) void k_pv_mfma(const u16* __restrict__ Pb,
                                                 const u16* __restrict__ Vt,
                                                 u16* __restrict__ Yp,
                                                 int L, int F, int ksplit)
{
    __shared__ u16 lAs[8192], lBs[8192];
    const int tid = threadIdx.x, wave = tid >> 6, lane = tid & 63;
    const int bi = blockIdx.z / ksplit, ks = blockIdx.z % ksplit;
    const int kf = L / ksplit;
    f32x4 acc[4][4];
#pragma unroll
    for (int i = 0; i < 4; ++i)
#pragma unroll
        for (int j = 0; j < 4; ++j) acc[i][j] = (f32x4){0.f, 0.f, 0.f, 0.f};
    mfma_nt(Pb + (size_t)bi * L * L + (size_t)blockIdx.y * 128 * L + (size_t)ks * kf, L,
            Vt + (size_t)bi * F * L + (size_t)blockIdx.x * 128 * L + (size_t)ks * kf, L,
            kf / 32, wave, lane, lAs, lBs, acc);
    const int wm = (wave >> 1) * 64, wn = (wave & 1) * 64;
    const int rb = (lane >> 4) * 4, cb = lane & 15;
    u16* Cp = Yp + ((size_t)(ks * Bb + bi) * L) * F;
#pragma unroll
    for (int i = 0; i < 4; ++i)
#pragma unroll
        for (int reg = 0; reg < 4; ++reg) {
            int gm = blockIdx.y * 128 + wm + i * 16 + rb + reg;
#pragma unroll
            for (int j = 0; j < 4; ++j) {
                int gn = blockIdx.x * 128 + wn + j * 16 + cb;
                Cp[(size_t)gm * F + gn] = f2bf(acc[i][j][reg]);
            }
        }
}

// ---------------------------------------------------------------------------
// Sum NSPLIT Yp partials + scatter to catbT[pix][cin].
// ---------------------------------------------------------------------------
template<int NSPLIT>
__global__ void k_unpatch(const u16* __restrict__ Yp, u16* __restrict__ catbT,
                          int ps, int outn, int L, int F, int cbase)
{
    size_t idx = (size_t)blockIdx.x * 256 + threadIdx.x;
    size_t total = (size_t)Bb * L * F / 4;
    if (idx >= total) return;
    const size_t pstr = (size_t)Bb * L * F;
    int f0 = (int)((idx * 4) % F);
    size_t t2 = (idx * 4) / F;
    int l = (int)(t2 % L);
    int bi = (int)(t2 / L);
    size_t off = ((size_t)bi * L + l) * F + f0;
    float s[4] = {0.f, 0.f, 0.f, 0.f};
#pragma unroll
    for (int sp = 0; sp < NSPLIT; ++sp) {
        uint2 u = *(const uint2*)&Yp[(size_t)sp * pstr + off];
        s[0] += bf2f((u16)(u.x & 0xffffu));
        s[1] += bf2f((u16)(u.x >> 16));
        s[2] += bf2f((u16)(u.y & 0xffffu));
        s[3] += bf2f((u16)(u.y >> 16));
    }
    int hw = ps * ps;
    int c = cbase + f0 / hw, r0 = f0 % hw;
    int ti = l / (outn * outn); int rem = l % (outn * outn);
    int oh = rem / outn, ow = rem % outn;
    int n = bi * Tt + ti;
    int py = r0 / ps, px = r0 % ps;   // r0 4-aligned -> same row, 4 consecutive px
    size_t base = ((size_t)n * PIX + (size_t)(oh * ps + py) * 64 + ow * ps + px) * Dc + c;
#pragma unroll
    for (int e = 0; e < 4; ++e)
        catbT[base + (size_t)e * Dc] = f2bf(s[e]);
}

// ---------------------------------------------------------------------------
// Output conv 3x3 as implicit NT GEMM over catbT, tap-split 2-way, BK=64
// pairing (2 (tap,kc) chunks per barrier; 9 pairs per split).
// grid (512, 2) = 1024 blocks. bf16 [pix][cout] partials.
// ---------------------------------------------------------------------------
__global__ __launch_bounds__(256) void k_conv_mfma(const u16* __restrict__ catbT,
                                                   const u16* __restrict__ WoT,
                                                   const u16* __restrict__ zp,
                                                   u16* __restrict__ Cpart)
{
    __shared__ u16 lAs[8192], lBs[8192];
    const int tid = threadIdx.x, wave = tid >> 6, lane = tid & 63;
    const int pix0 = blockIdx.x * 128;
    const int sp = blockIdx.y;
    const int r = lane >> 2;
    const int kq8 = ((lane & 3) ^ ((r >> 1) & 3)) * 8;   // swizzled source seg
    int yb[2], xb[2], nn[2];
#pragma unroll
    for (int s = 0; s < 2; ++s) {
        int pg = pix0 + wave * 32 + r + s * 16;
        nn[s] = pg >> 12; yb[s] = (pg >> 6) & 63; xb[s] = pg & 63;
    }
    const u16* gb_base = WoT + (size_t)(wave * 32 + r) * 128 + kq8;
    f32x4 acc[4][4];
#pragma unroll
    for (int i = 0; i < 4; ++i)
#pragma unroll
        for (int j = 0; j < 4; ++j) acc[i][j] = (f32x4){0.f, 0.f, 0.f, 0.f};
    for (int tp = 0; tp < 9; ++tp) {
        const int t0 = sp * 18 + tp * 2;
        __syncthreads();
#pragma unroll
        for (int h = 0; h < 2; ++h) {
            const int t = t0 + h;
            const int tap = t >> 2, kc = t & 3;
            const int dy = tap / 3 - 1, dx = tap % 3 - 1;
            const u16* ga[2];
#pragma unroll
            for (int s = 0; s < 2; ++s) {
                int y = yb[s] + dy, xx = xb[s] + dx;
                bool ok = ((unsigned)y < 64u) && ((unsigned)xx < 64u);
                ga[s] = ok ? catbT + (((size_t)(nn[s] << 12) + y * 64 + xx) << 7) + kq8 + kc * 32 : zp;
            }
            const u16* gb = gb_base + tap * 16384 + kc * 32;
            GLOAD16(ga[0], lAs + h * 4096 + wave * 1024);
            GLOAD16(ga[1], lAs + h * 4096 + wave * 1024 + 512);
            GLOAD16(gb, lBs + h * 4096 + wave * 1024);
            GLOAD16(gb + 2048, lBs + h * 4096 + wave * 1024 + 512);
        }
        __syncthreads();
        mfma_chunk(lAs, lBs, wave, lane, acc);
        mfma_chunk(lAs + 4096, lBs + 4096, wave, lane, acc);
    }
    const int wm = (wave >> 1) * 64, wn = (wave & 1) * 64;
    const int rb = (lane >> 4) * 4, cb = lane & 15;
    u16* Cp = Cpart + (size_t)sp * 8388608;
#pragma unroll
    for (int i = 0; i < 4; ++i)
#pragma unroll
        for (int reg = 0; reg < 4; ++reg) {
            int gm = pix0 + wm + i * 16 + rb + reg;          // global pixel
#pragma unroll
            for (int j = 0; j < 4; ++j) {
                int gn = wn + j * 16 + cb;                   // cout
                Cp[(size_t)gm * 128 + gn] = f2bf(acc[i][j][reg]);
            }
        }
}

// ---------------------------------------------------------------------------
// Conv finalize: out = leaky(sum of 2 bf16 partials + bias), NCHW fp32.
// ---------------------------------------------------------------------------
__global__ __launch_bounds__(256) void k_cfin(const u16* __restrict__ Cpart,
                                              const float* __restrict__ bo,
                                              float* __restrict__ outp)
{
    const int pg0 = blockIdx.x * 64;
    const int lane = threadIdx.x & 63, wv = threadIdx.x >> 6;
    const int pix = pg0 + lane;
    const int n = pix >> 12, p = pix & 4095;
    const u16* r0 = Cpart + (size_t)pix * 128 + wv * 32;
    const u16* r1 = r0 + 8388608;
#pragma unroll
    for (int c4 = 0; c4 < 8; ++c4) {
        uint2 a = *(const uint2*)(r0 + c4 * 4);
        uint2 b = *(const uint2*)(r1 + c4 * 4);
        float s[4];
        s[0] = bf2f((u16)(a.x & 0xffffu)) + bf2f((u16)(b.x & 0xffffu));
        s[1] = bf2f((u16)(a.x >> 16))     + bf2f((u16)(b.x >> 16));
        s[2] = bf2f((u16)(a.y & 0xffffu)) + bf2f((u16)(b.y & 0xffffu));
        s[3] = bf2f((u16)(a.y >> 16))     + bf2f((u16)(b.y >> 16));
#pragma unroll
        for (int e = 0; e < 4; ++e) {
            int cout = wv * 32 + c4 * 4 + e;
            float v = s[e] + bo[cout];
            v = (v >= 0.f) ? v : 0.2f * v;
            outp[((size_t)n * Dc + cout) * PIX + p] = v;
        }
    }
}

// ---------------------------------------------------------------------------
extern "C" void kernel_launch(void* const* d_in, const int* in_sizes, int n_in,
                              void* d_out, int out_size, void* d_ws, size_t ws_size,
                              hipStream_t stream)
{
    (void)in_sizes; (void)n_in; (void)out_size; (void)ws_size;
    const float* x    = (const float*)d_in[0];
    const float* mI   = (const float*)d_in[1];
    const float* dmap = (const float*)d_in[2];
    const float* wq   = (const float*)d_in[3];
    const float* bq   = (const float*)d_in[4];
    const float* wk   = (const float*)d_in[5];
    const float* bk   = (const float*)d_in[6];
    const float* wv   = (const float*)d_in[7];
    const float* bv   = (const float*)d_in[8];
    const float* wvle = (const float*)d_in[9];
    const float* bvle = (const float*)d_in[10];
    const float* wd1  = (const float*)d_in[11];
    const float* bd1  = (const float*)d_in[12];
    const float* wd2  = (const float*)d_in[13];
    const float* bd2  = (const float*)d_in[14];
    const float* wo   = (const float*)d_in[15];
    const float* bo   = (const float*)d_in[16];

    // workspace layout (~180 MB)
    char* w8 = (char*)d_ws;
    u16*   v_bf  = (u16*)(w8);                    // 16 MB
    u16*   Xt    = (u16*)(w8 + 0x1000000);        // 16 MB
    u16*   catbT = (u16*)(w8 + 0x2000000);        // 16 MB
    u16*   Qp0   = (u16*)(w8 + 0x3000000);        // 8 MB each (patched Q/K, both scales)
    u16*   Kp0   = (u16*)(w8 + 0x3800000);
    u16*   Qp1   = (u16*)(w8 + 0x4000000);
    u16*   Kp1   = (u16*)(w8 + 0x4800000);
    u16*   Vt    = (u16*)(w8 + 0x5000000);        // 8 MB
    u16*   Sb    = (u16*)(w8 + 0x5800000);        // 32 MB bf16 S partials
    u16*   Pb    = (u16*)(w8 + 0x7800000);        // 16 MB
    u16*   Yp    = (u16*)(w8 + 0x8800000);        // 32 MB pv partials
    u16*   Cpart = (u16*)(w8 + 0x5800000);        // conv partials: reuse Sb (dead after softmax i=1)
    // d1b (64 MB) ALIASES Qp0..Sb: depth path runs strictly before qkv/attn
    u16*   d1b   = (u16*)(w8 + 0x3000000);
    float* dep   = (float*)(w8 + 0xA800000);
    float* maskf = (float*)(w8 + 0xA840000);
    float* smed  = (float*)(w8 + 0xA844000);
    float* smaxA = (float*)(w8 + 0xA848000);
    float* sminA = (float*)(w8 + 0xA84C000);
    u16*   Wqkv  = (u16*)(w8 + 0xA850000);
    u16*   WoT   = (u16*)(w8 + 0xA868000);
    u16*   zp    = (u16*)(w8 + 0xA8B0000);
    float* part  = (float*)(w8 + 0xA8C0000);      // 2 MB
    float* outp  = (float*)d_out;

    hipMemcpyAsync(outp + 8388608, dmap, (size_t)16 * 65536 * sizeof(float),
                   hipMemcpyDeviceToDevice, stream);
    hipMemsetAsync(zp, 0, 256, stream);

    dim3 blk(256);
    // depth path first (d1b aliases Qp/Sb scratch)
    k_d1<<<dim3(32, 16), blk, 0, stream>>>(dmap, wd1, bd1, d1b);
    k_d2p<<<dim3(4, 16, 8), blk, 0, stream>>>(d1b, wd2, part);
    k_dfin<<<dim3(256), blk, 0, stream>>>(part, bd2, dep);

    k_prep<<<dim3(768), blk, 0, stream>>>(wq, wk, wv, wo, Wqkv, WoT);
    k_xt<<<dim3(64, 16), blk, 0, stream>>>(x, Xt);
    k_qkv_mfma<<<dim3(32, 3, 16), blk, 0, stream>>>(Wqkv, Xt, bq, bk, bv,
                                                    Qp0, Kp0, Qp1, Kp1, v_bf);
    k_vdw<<<dim3(128, 16), blk, 0, stream>>>(x, wvle, bvle, v_bf);

    for (int i = 0; i < 2; ++i) {
        const int ps = (i == 0) ? 4 : 8;
        const int outn = 64 / ps;
        const int L = Tt * outn * outn;        // 2048 / 512
        const int F = 64 * ps * ps;            // 1024 / 4096
        const int cbase = i * 64;
        const float scale = 1.0f / sqrtf((float)F);
        const int ksplit  = (i == 0) ? 2 : 16; // qkT grids: 1024 / 512 blocks
        const int pvsplit = 4;                 // pv grids: 1024 / 1024 blocks
        const u16* Qp = (i == 0) ? Qp0 : Qp1;
        const u16* Kp = (i == 0) ? Kp0 : Kp1;

        if (i == 0) k_stats2<4><<<dim3(Bb * L * 16 / 256), blk, 0, stream>>>(mI, dep, maskf, smed, smaxA, sminA, outn, L);
        else        k_stats2<8><<<dim3(Bb * L * 64 / 256), blk, 0, stream>>>(mI, dep, maskf, smed, smaxA, sminA, outn, L);

        const int pgrid = (int)(((size_t)Bb * L * F / 4 + 255) / 256);
        k_patchT<<<dim3(pgrid), blk, 0, stream>>>(v_bf, Vt, ps, outn, L, F, cbase);

        k_qkT_mfma<<<dim3(L / 128, L / 128, Bb * ksplit), blk, 0, stream>>>(Qp, Kp, Sb, L, F, ksplit, scale);

        if (i == 0) k_softmax<8, 2><<<dim3(L, Bb), blk, 0, stream>>>(Sb, Pb, maskf, smed, smaxA, sminA, L);
        else        k_softmax<2, 16><<<dim3(L, Bb), blk, 0, stream>>>(Sb, Pb, maskf, smed, smaxA, sminA, L);

        k_pv_mfma<<<dim3(F / 128, L / 128, Bb * pvsplit), blk, 0, stream>>>(Pb, Vt, Yp, L, F, pvsplit);
        k_unpatch<4><<<dim3(pgrid), blk, 0, stream>>>(Yp, catbT, ps, outn, L, F, cbase);
    }

    k_conv_mfma<<<dim3(512, 2), blk, 0, stream>>>(catbT, WoT, zp, Cpart);
    k_cfin<<<dim3(1024), blk, 0, stream>>>(Cpart, bo, outp);
}

// Round 10
// 438.660 us; speedup vs baseline: 1.0844x; 1.0844x over previous
//
#include <hip/hip_runtime.h>
#include <cmath>

typedef unsigned short u16;
typedef __attribute__((ext_vector_type(8))) __bf16 bf16x8;
typedef __attribute__((ext_vector_type(4))) float f32x4;

constexpr int Bb = 2, Tt = 8, Dc = 128, PIX = 4096; // b=2, c=128, 64x64 imgs

__device__ inline u16 f2bf(float f) {
    unsigned u = __builtin_bit_cast(unsigned, f);
    u += 0x7fffu + ((u >> 16) & 1u);
    return (u16)(u >> 16);
}
__device__ inline float bf2f(u16 h) {
    unsigned u = ((unsigned)h) << 16;
    return __builtin_bit_cast(float, u);
}

#define GLOAD16(gp, lp) __builtin_amdgcn_global_load_lds( \
    (const __attribute__((address_space(1))) void*)(const void*)(gp), \
    (__attribute__((address_space(3))) void*)(void*)(lp), 16, 0, 0)

// ---------------------------------------------------------------------------
// bf16 NT MFMA core, BK=64: two 32-K chunks per barrier pair in 32KB LDS.
// (r9 measured: net win vs BK=32 -- pv/qkT/conv left the top-5.)
// ---------------------------------------------------------------------------
__device__ inline void mfma_chunk(const u16* lAs, const u16* lBs, int wave, int lane,
                                  f32x4 (&acc)[4][4])
{
    const int wm = (wave >> 1) * 64, wn = (wave & 1) * 64;
    const int fr = lane & 15;
    const int q4 = lane >> 4;                         // wanted global k-quarter
    const int sw = (q4 ^ ((fr >> 1) & 3)) * 8;        // swizzled storage seg
    bf16x8 av[4], bv[4];
#pragma unroll
    for (int i = 0; i < 4; ++i) av[i] = *(const bf16x8*)&lAs[(wm + i * 16 + fr) * 32 + sw];
#pragma unroll
    for (int j = 0; j < 4; ++j) bv[j] = *(const bf16x8*)&lBs[(wn + j * 16 + fr) * 32 + sw];
#pragma unroll
    for (int i = 0; i < 4; ++i)
#pragma unroll
        for (int j = 0; j < 4; ++j)
            acc[i][j] = __builtin_amdgcn_mfma_f32_16x16x32_bf16(av[i], bv[j], acc[i][j], 0, 0, 0);
}

// kChunks = number of 32-K chunks, must be EVEN.
__device__ inline void mfma_nt(const u16* A, int ldkA, const u16* B, int ldkB,
                               int kChunks, int wave, int lane,
                               u16* lAs, u16* lBs, f32x4 (&acc)[4][4])
{
    const int r = lane >> 2;                              // row within 16-group
    const int kq8 = ((lane & 3) ^ ((r >> 1) & 3)) * 8;    // swizzled source seg
    const u16* ga0 = A + (size_t)(wave * 32 + r) * ldkA + kq8;
    const u16* ga1 = ga0 + (size_t)16 * ldkA;
    const u16* gb0 = B + (size_t)(wave * 32 + r) * ldkB + kq8;
    const u16* gb1 = gb0 + (size_t)16 * ldkB;
    for (int kb = 0; kb < kChunks; kb += 2) {
        __syncthreads();                       // WAR: prior pair's ds_reads done
        GLOAD16(ga0 + kb * 32, lAs + wave * 1024);
        GLOAD16(ga1 + kb * 32, lAs + wave * 1024 + 512);
        GLOAD16(gb0 + kb * 32, lBs + wave * 1024);
        GLOAD16(gb1 + kb * 32, lBs + wave * 1024 + 512);
        GLOAD16(ga0 + (kb + 1) * 32, lAs + 4096 + wave * 1024);
        GLOAD16(ga1 + (kb + 1) * 32, lAs + 4096 + wave * 1024 + 512);
        GLOAD16(gb0 + (kb + 1) * 32, lBs + 4096 + wave * 1024);
        GLOAD16(gb1 + (kb + 1) * 32, lBs + 4096 + wave * 1024 + 512);
        __syncthreads();                       // drains vmcnt(0) before barrier
        mfma_chunk(lAs, lBs, wave, lane, acc);
        mfma_chunk(lAs + 4096, lBs + 4096, wave, lane, acc);
    }
}

// ---------------------------------------------------------------------------
// Weight prep: Wqkv[3*128][128] bf16 stacked; WoT[tap][cout][cin] bf16.
// ---------------------------------------------------------------------------
__global__ void k_prep(const float* __restrict__ wq, const float* __restrict__ wk,
                       const float* __restrict__ wv, const float* __restrict__ wo,
                       u16* __restrict__ Wqkv, u16* __restrict__ WoT)
{
    int idx = blockIdx.x * 256 + threadIdx.x;
    if (idx < 49152) {
        const float* w = idx < 16384 ? wq : (idx < 32768 ? wk : wv);
        Wqkv[idx] = f2bf(w[idx & 16383]);
    }
    int j = idx - 49152;
    if (j >= 0 && j < 147456) {
        int tap = j / 16384, rem = j % 16384;  // rem = cout*128+cin
        WoT[j] = f2bf(wo[(size_t)rem * 9 + tap]);
    }
}

// ---------------------------------------------------------------------------
// Xt[n][pix][cin] bf16 from x[n][cin][pix] fp32 (LDS transpose, 64-pix tiles)
// ---------------------------------------------------------------------------
__global__ __launch_bounds__(256) void k_xt(const float* __restrict__ x, u16* __restrict__ Xt)
{
    __shared__ float ls[128 * 65];
    const int n = blockIdx.y, pix0 = blockIdx.x * 64;
#pragma unroll
    for (int rep = 0; rep < 32; ++rep) {
        int idx = rep * 256 + threadIdx.x;
        int cin = idx >> 6, p = idx & 63;
        ls[cin * 65 + p] = x[((size_t)n * Dc + cin) * PIX + pix0 + p];
    }
    __syncthreads();
#pragma unroll
    for (int rep = 0; rep < 32; ++rep) {
        int idx = rep * 256 + threadIdx.x;
        int p = idx >> 7, cin = idx & 127;
        Xt[((size_t)n * PIX + pix0 + p) * Dc + cin] = f2bf(ls[cin * 65 + p]);
    }
}

// ---------------------------------------------------------------------------
// Fused QKV GEMM; Q/K scattered directly into patched layouts (both scales).
// grid (32 pixtiles, 3 mt, 16 imgs) = 1536 blocks.
// ---------------------------------------------------------------------------
__global__ __launch_bounds__(256) void k_qkv_mfma(const u16* __restrict__ Wqkv,
                                                  const u16* __restrict__ Xt,
                                                  const float* __restrict__ bq,
                                                  const float* __restrict__ bk,
                                                  const float* __restrict__ bv,
                                                  u16* __restrict__ Qp0, u16* __restrict__ Kp0,
                                                  u16* __restrict__ Qp1, u16* __restrict__ Kp1,
                                                  u16* __restrict__ v_bf)
{
    __shared__ u16 lAs[8192], lBs[8192];
    const int tid = threadIdx.x, wave = tid >> 6, lane = tid & 63;
    const int mt = blockIdx.y, n = blockIdx.z, px0 = blockIdx.x * 128;
    f32x4 acc[4][4];
#pragma unroll
    for (int i = 0; i < 4; ++i)
#pragma unroll
        for (int j = 0; j < 4; ++j) acc[i][j] = (f32x4){0.f, 0.f, 0.f, 0.f};
    mfma_nt(Wqkv + (size_t)mt * 128 * 128, 128,
            Xt + ((size_t)n * PIX + px0) * 128, 128, 4, wave, lane, lAs, lBs, acc);
    const int wm = (wave >> 1) * 64, wn = (wave & 1) * 64;
    const int rb = (lane >> 4) * 4, cb = lane & 15;
    const int bi = n >> 3, ti = n & 7;
    if (mt < 2) {
        const float* bp = (mt == 0) ? bq : bk;
        u16* d0 = (mt == 0) ? Qp0 : Kp0;
        u16* d1 = (mt == 0) ? Qp1 : Kp1;
#pragma unroll
        for (int i = 0; i < 4; ++i)
#pragma unroll
            for (int reg = 0; reg < 4; ++reg) {
                int c = wm + i * 16 + rb + reg;          // 0..127
                float bias = bp[c];
#pragma unroll
                for (int j = 0; j < 4; ++j) {
                    int pix = px0 + wn + j * 16 + cb;
                    int y = pix >> 6, x = pix & 63;
                    u16 val = f2bf(acc[i][j][reg] + bias);
                    if (c < 64) {                         // scale 0 (ps=4)
                        int l = ti * 256 + (y >> 2) * 16 + (x >> 2);
                        int f = c * 16 + (y & 3) * 4 + (x & 3);
                        d0[((size_t)bi * 2048 + l) * 1024 + f] = val;
                    } else {                              // scale 1 (ps=8)
                        int l = ti * 64 + (y >> 3) * 8 + (x >> 3);
                        int f = (c - 64) * 64 + (y & 7) * 8 + (x & 7);
                        d1[((size_t)bi * 512 + l) * 4096 + f] = val;
                    }
                }
            }
    } else {
#pragma unroll
        for (int i = 0; i < 4; ++i)
#pragma unroll
            for (int reg = 0; reg < 4; ++reg) {
                int c = wm + i * 16 + rb + reg;
                float bias = bv[c];
#pragma unroll
                for (int j = 0; j < 4; ++j) {
                    int pix = px0 + wn + j * 16 + cb;
                    v_bf[((size_t)n * Dc + c) * PIX + pix] = f2bf(acc[i][j][reg] + bias);
                }
            }
    }
}

// ---------------------------------------------------------------------------
// Depthwise 3x3 add into bf16 v_all: block per (c,n), x staged in LDS once.
// grid (128, 16).
// ---------------------------------------------------------------------------
__global__ __launch_bounds__(256) void k_vdw(const float* __restrict__ X,
                                             const float* __restrict__ wvle,
                                             const float* __restrict__ bvle,
                                             u16* __restrict__ v_bf)
{
    __shared__ float ls[4096];
    const int c = blockIdx.x, n = blockIdx.y;
    const int tid = threadIdx.x;
    const float* xp = X + ((size_t)n * Dc + c) * PIX;
#pragma unroll
    for (int r = 0; r < 4; ++r)
        *(float4*)&ls[r * 1024 + tid * 4] = *(const float4*)&xp[r * 1024 + tid * 4];
    __syncthreads();
    float w[9];
#pragma unroll
    for (int t = 0; t < 9; ++t) w[t] = wvle[c * 9 + t];   // uniform -> s_load
    const float bias = bvle[c];
    const int x = tid & 63, y0 = (tid >> 6) * 16;
    const bool xl = (x > 0), xr = (x < 63);
    u16* vp = v_bf + ((size_t)n * Dc + c) * PIX;
#pragma unroll
    for (int r = 0; r < 16; ++r) {
        int y = y0 + r;
        float s = bias;
#pragma unroll
        for (int ky = 0; ky < 3; ++ky) {
            int yy = y + ky - 1;
            if (yy < 0 || yy > 63) continue;              // wave-uniform edges
            const float* row = &ls[yy * 64];
            float m  = row[x];
            float lv = xl ? row[x - 1] : 0.f;
            float rv = xr ? row[x + 1] : 0.f;
            s += w[ky * 3 + 0] * lv + w[ky * 3 + 1] * m + w[ky * 3 + 2] * rv;
        }
        int idx = y * 64 + x;
        vp[idx] = f2bf(bf2f(vp[idx]) + s);
    }
}

// ---------------------------------------------------------------------------
// Depth path, kernel 1: d1[n][c][128][128] = relu(conv(dm, wd1, s2, p1)) bf16.
// ---------------------------------------------------------------------------
__global__ __launch_bounds__(256) void k_d1(const float* __restrict__ dm,
                                            const float* __restrict__ wd1,
                                            const float* __restrict__ bd1,
                                            u16* __restrict__ d1b)
{
    __shared__ float ls[17 * 132];
    const int n = blockIdx.y;
    const int yt = blockIdx.x >> 1, xh = blockIdx.x & 1;
    const int Y0 = yt * 8;
    const int tid = threadIdx.x;
    const float* dmp = dm + (size_t)n * 65536;
    for (int idx = tid; idx < 17 * 132; idx += 256) {
        int row = idx / 132, cl = idx % 132;
        int gr = 2 * Y0 - 1 + row;
        int gc = 128 * xh - 1 + cl;
        float v = 0.f;
        if (gr >= 0 && gr < 256 && gc >= 0 && gc < 256 && cl < 129) v = dmp[gr * 256 + gc];
        ls[idx] = v;
    }
    __syncthreads();
    const int Xl = tid & 63;
    const int Yl0 = tid >> 6;                 // rows Yl0 and Yl0+4
    float in0[9], in1[9];
#pragma unroll
    for (int jy = 0; jy < 3; ++jy)
#pragma unroll
        for (int jx = 0; jx < 3; ++jx) {
            in0[jy * 3 + jx] = ls[(2 * Yl0 + jy) * 132 + 2 * Xl + jx];
            in1[jy * 3 + jx] = ls[(2 * (Yl0 + 4) + jy) * 132 + 2 * Xl + jx];
        }
    const int X = 64 * xh + Xl;
    u16* outbase = d1b + (size_t)n * Dc * 16384 + (size_t)Y0 * 128 + X;
    for (int c = 0; c < 128; ++c) {
        const float* w1 = wd1 + c * 9;        // uniform -> s_load
        float a0 = bd1[c], a1 = a0;
#pragma unroll
        for (int t = 0; t < 9; ++t) { a0 += w1[t] * in0[t]; a1 += w1[t] * in1[t]; }
        u16* ob = outbase + (size_t)c * 16384;
        ob[(size_t)Yl0 * 128]       = f2bf(fmaxf(a0, 0.f));
        ob[(size_t)(Yl0 + 4) * 128] = f2bf(fmaxf(a1, 0.f));
    }
}

// ---------------------------------------------------------------------------
// Depth path, kernel 2: partial conv2 over 16-channel groups.
// ---------------------------------------------------------------------------
__global__ __launch_bounds__(256) void k_d2p(const u16* __restrict__ d1b,
                                             const float* __restrict__ wd2,
                                             float* __restrict__ part)
{
    __shared__ u16 ls[33 * 136];              // payload at cl 8..135, zero at cl 7
    const int yt = blockIdx.x, n = blockIdx.y, cg = blockIdx.z;
    const int tid = threadIdx.x;
    const int y0 = yt * 16;
    if (tid < 33) ls[tid * 136 + 7] = 0;
    const int x = tid & 63;
    const int yl0 = (tid >> 6) * 4;
    float acc[4] = {0.f, 0.f, 0.f, 0.f};
    for (int c = 0; c < 16; ++c) {
        const u16* src = d1b + ((size_t)n * Dc + cg * 16 + c) * 16384;
        __syncthreads();
        for (int idx = tid; idx < 33 * 16; idx += 256) {
            int row = idx >> 4, s = idx & 15;
            int gr = 2 * y0 - 1 + row;
            uint4 v = make_uint4(0, 0, 0, 0);
            if (gr >= 0 && gr < 128) v = *(const uint4*)(src + gr * 128 + s * 8);
            *(uint4*)&ls[row * 136 + 8 + s * 8] = v;
        }
        __syncthreads();
        const float* w2 = wd2 + (cg * 16 + c) * 9;   // uniform -> s_load
        float w[9];
#pragma unroll
        for (int t = 0; t < 9; ++t) w[t] = w2[t];
#pragma unroll
        for (int r = 0; r < 4; ++r) {
            int yl = yl0 + r;
#pragma unroll
            for (int ky = 0; ky < 3; ++ky) {
                const u16* rp = &ls[(2 * yl + ky) * 136 + 2 * x + 7];
                float v0 = bf2f(rp[0]);
                unsigned pr = *(const unsigned*)(rp + 1);
                float v1 = bf2f((u16)(pr & 0xffffu));
                float v2 = bf2f((u16)(pr >> 16));
                acc[r] += w[ky * 3 + 0] * v0 + w[ky * 3 + 1] * v1 + w[ky * 3 + 2] * v2;
            }
        }
    }
    float* pp = part + ((size_t)cg * 16 + n) * PIX;
#pragma unroll
    for (int r = 0; r < 4; ++r)
        pp[(y0 + yl0 + r) * 64 + x] = acc[r];
}

// Depth path, kernel 3: dep = relu(sum_cg part + bd2). grid (256)
__global__ void k_dfin(const float* __restrict__ part, const float* __restrict__ bd2,
                       float* __restrict__ dep)
{
    int idx = blockIdx.x * 256 + threadIdx.x;
    float s = bd2[0];
#pragma unroll
    for (int cg = 0; cg < 8; ++cg) s += part[(size_t)cg * 65536 + idx];
    dep[idx] = fmaxf(s, 0.f);
}

// ---------------------------------------------------------------------------
// Wave-parallel per-token stats (min/max/mask butterfly, exact median rank).
// ---------------------------------------------------------------------------
template<int PS>
__global__ __launch_bounds__(256) void k_stats2(const float* __restrict__ mI,
                                                const float* __restrict__ dep,
                                                float* __restrict__ maskf,
                                                float* __restrict__ smed,
                                                float* __restrict__ smaxA,
                                                float* __restrict__ sminA,
                                                int outn, int L)
{
    constexpr int HW = PS * PS;              // 16 or 64
    constexpr int TPB = 256 / HW;
    const int tok = blockIdx.x * TPB + threadIdx.x / HW;
    const int el  = threadIdx.x % HW;
    if (tok >= Bb * L) return;
    const int bi = tok / L, l = tok % L;
    const int ti = l / (outn * outn); const int rem = l % (outn * outn);
    const int oh = rem / outn, ow = rem % outn;
    const int n = bi * Tt + ti;
    const int py = el / PS, px = el % PS;
    const size_t off = (size_t)n * PIX + (size_t)(oh * PS + py) * 64 + ow * PS + px;
    const float mv = mI[off];
    const float dv = dep[off];
    float msum = mv, vmin = dv, vmax = dv;
#pragma unroll
    for (int o = HW / 2; o > 0; o >>= 1) {
        msum += __shfl_xor(msum, o);
        vmin = fminf(vmin, __shfl_xor(vmin, o));
        vmax = fmaxf(vmax, __shfl_xor(vmax, o));
    }
    const int gbase = (threadIdx.x & 63) & ~(HW - 1);
    int cl = 0, ce = 0;
#pragma unroll
    for (int b2 = 0; b2 < HW; ++b2) {
        float vb = __shfl(dv, gbase + b2);
        cl += (vb < dv);
        ce += (vb == dv);
    }
    constexpr int kk = (HW - 1) / 2;
    if (el == 0) {
        maskf[tok] = (msum / (float)HW > 0.5f) ? 1.f : 0.f;
        smaxA[tok] = 1.f / (1.f + __expf(-vmax));
        sminA[tok] = 1.f / (1.f + __expf(-vmin));
    }
    if (cl <= kk && kk < cl + ce)
        smed[tok] = 1.f / (1.f + __expf(-dv));
}

// V transposed patch: Vt[bi][f][l] bf16. 4 consecutive l per thread.
__global__ void k_patchT(const u16* __restrict__ v_bf, u16* __restrict__ Vt,
                         int ps, int outn, int L, int F, int cbase)
{
    size_t idx = (size_t)blockIdx.x * 256 + threadIdx.x;
    size_t total = (size_t)Bb * F * L / 4;
    if (idx >= total) return;
    int l0 = (int)((idx * 4) % L);
    size_t t2 = (idx * 4) / L;
    int f = (int)(t2 % F);
    int bi = (int)(t2 / F);
    int hw = ps * ps;
    int c = cbase + f / hw, r = f % hw;
    int py = r / ps, px = r % ps;
    int ti = l0 / (outn * outn); int rem = l0 % (outn * outn);
    int oh = rem / outn, ow0 = rem % outn;
    size_t base = ((size_t)(bi * Tt + ti) * Dc + c) * PIX + (oh * ps + py) * 64 + px;
    u16 out4[4];
#pragma unroll
    for (int e = 0; e < 4; ++e) out4[e] = v_bf[base + (size_t)(ow0 + e) * ps];
    *(uint2*)&Vt[((size_t)bi * F + f) * L + l0] = *(uint2*)out4;
}

// ---------------------------------------------------------------------------
// S = scale * Q K^T (LDS MFMA BK=64), bf16 partials.
// grid (L/128, L/128, Bb*ksplit).
// ---------------------------------------------------------------------------
__global__ __launch_bounds__(256) void k_qkT_mfma(const u16* __restrict__ Qp,
                                                  const u16* __restrict__ Kp,
                                                  u16* __restrict__ S,
                                                  int L, int F, int ksplit, float scale)
{
    __shared__ u16 lAs[8192], lBs[8192];
    const int tid = threadIdx.x, wave = tid >> 6, lane = tid & 63;
    const int bi = blockIdx.z / ksplit, ks = blockIdx.z % ksplit;
    const int kf = F / ksplit;
    f32x4 acc[4][4];
#pragma unroll
    for (int i = 0; i < 4; ++i)
#pragma unroll
        for (int j = 0; j < 4; ++j) acc[i][j] = (f32x4){0.f, 0.f, 0.f, 0.f};
    mfma_nt(Qp + (size_t)bi * L * F + (size_t)blockIdx.y * 128 * F + (size_t)ks * kf, F,
            Kp + (size_t)bi * L * F + (size_t)blockIdx.x * 128 * F + (size_t)ks * kf, F,
            kf / 32, wave, lane, lAs, lBs, acc);
    const int wm = (wave >> 1) * 64, wn = (wave & 1) * 64;
    const int rb = (lane >> 4) * 4, cb = lane & 15;
    u16* Cp = S + ((size_t)ks * Bb + bi) * L * L;
#pragma unroll
    for (int i = 0; i < 4; ++i)
#pragma unroll
        for (int reg = 0; reg < 4; ++reg) {
            int gm = blockIdx.y * 128 + wm + i * 16 + rb + reg;
#pragma unroll
            for (int j = 0; j < 4; ++j) {
                int gn = blockIdx.x * 128 + wn + j * 16 + cb;
                Cp[(size_t)gm * L + gn] = f2bf(acc[i][j][reg] * scale);
            }
        }
}

// ---------------------------------------------------------------------------
// 3-head softmax, r10: thread owns NPAIR pairs of ADJACENT columns with
// wave-contiguous mapping k = e*512 + tid*2 -- every S read is one u32 with
// consecutive lanes at consecutive addresses (256B/instr coalesced), mask
// and sigmoid lookups are coalesced float2 loads, P store is one u32/lane.
// (r9's k0=tid*NV mapping put 16B thread-stride on 4B loads -> 54us kernel,
// transaction-issue bound at 18% VALU / 8% HBM. This restores coalescing.)
// ---------------------------------------------------------------------------
__device__ inline float blockMax(float v, float* sh) {
#pragma unroll
    for (int o = 32; o > 0; o >>= 1) v = fmaxf(v, __shfl_down(v, o));
    __syncthreads();
    if ((threadIdx.x & 63) == 0) sh[threadIdx.x >> 6] = v;
    __syncthreads();
    return fmaxf(fmaxf(sh[0], sh[1]), fmaxf(sh[2], sh[3]));
}
__device__ inline float blockSum(float v, float* sh) {
#pragma unroll
    for (int o = 32; o > 0; o >>= 1) v += __shfl_down(v, o);
    __syncthreads();
    if ((threadIdx.x & 63) == 0) sh[threadIdx.x >> 6] = v;
    __syncthreads();
    return sh[0] + sh[1] + sh[2] + sh[3];
}

template<int NPAIR, int NSPLIT>
__global__ __launch_bounds__(256) void k_softmax(const u16* __restrict__ S,
                                                 u16* __restrict__ Pb,
                                                 const float* __restrict__ maskf,
                                                 const float* __restrict__ smed,
                                                 const float* __restrict__ smaxA,
                                                 const float* __restrict__ sminA,
                                                 int L)
{
    __shared__ float sred[4];
    const int bi = blockIdx.y, q = blockIdx.x;
    const size_t pstr = (size_t)Bb * L * L;
    const u16* row = S + (size_t)bi * L * L + (size_t)q * L;
    u16* prow = Pb + (size_t)bi * L * L + (size_t)q * L;
    const float* mk  = maskf + bi * L;
    const float* s0p = smed  + bi * L;
    const float* s1p = smaxA + bi * L;
    const float* s2p = sminA + bi * L;
    const int tid = threadIdx.x;
    float a0[2 * NPAIR], a1[2 * NPAIR], a2[2 * NPAIR];
    float m0 = -3.4e38f, m1 = -3.4e38f, m2 = -3.4e38f;
#pragma unroll
    for (int e = 0; e < NPAIR; ++e) {
        int k = e * 512 + tid * 2;
        unsigned u = *(const unsigned*)&row[k];
        float sva = bf2f((u16)(u & 0xffffu));
        float svb = bf2f((u16)(u >> 16));
#pragma unroll
        for (int s2 = 1; s2 < NSPLIT; ++s2) {
            unsigned w = *(const unsigned*)&row[(size_t)s2 * pstr + k];
            sva += bf2f((u16)(w & 0xffffu));
            svb += bf2f((u16)(w >> 16));
        }
        float2 mv  = *(const float2*)&mk[k];
        float2 p0  = *(const float2*)&s0p[k];
        float2 p1  = *(const float2*)&s1p[k];
        float2 p2  = *(const float2*)&s2p[k];
        bool ma = mv.x > 0.5f, mb = mv.y > 0.5f;
        float v0a = ma ? -1e9f : sva * p0.x, v0b = mb ? -1e9f : svb * p0.y;
        float v1a = ma ? -1e9f : sva * p1.x, v1b = mb ? -1e9f : svb * p1.y;
        float v2a = ma ? -1e9f : sva * p2.x, v2b = mb ? -1e9f : svb * p2.y;
        a0[2 * e] = v0a; a0[2 * e + 1] = v0b;
        a1[2 * e] = v1a; a1[2 * e + 1] = v1b;
        a2[2 * e] = v2a; a2[2 * e + 1] = v2b;
        m0 = fmaxf(m0, fmaxf(v0a, v0b));
        m1 = fmaxf(m1, fmaxf(v1a, v1b));
        m2 = fmaxf(m2, fmaxf(v2a, v2b));
    }
    m0 = blockMax(m0, sred); m1 = blockMax(m1, sred); m2 = blockMax(m2, sred);
    float l0 = 0.f, l1 = 0.f, l2 = 0.f;
#pragma unroll
    for (int e = 0; e < 2 * NPAIR; ++e) {
        a0[e] = __expf(a0[e] - m0); l0 += a0[e];
        a1[e] = __expf(a1[e] - m1); l1 += a1[e];
        a2[e] = __expf(a2[e] - m2); l2 += a2[e];
    }
    l0 = blockSum(l0, sred); l1 = blockSum(l1, sred); l2 = blockSum(l2, sred);
    float c0 = 1.f / (3.f * l0), c1 = 1.f / (3.f * l1), c2 = 1.f / (3.f * l2);
#pragma unroll
    for (int e = 0; e < NPAIR; ++e) {
        int k = e * 512 + tid * 2;
        u16 oa = f2bf(a0[2 * e] * c0 + a1[2 * e] * c1 + a2[2 * e] * c2);
        u16 ob = f2bf(a0[2 * e + 1] * c0 + a1[2 * e + 1] * c1 + a2[2 * e + 1] * c2);
        unsigned pk = (unsigned)oa | ((unsigned)ob << 16);
        *(unsigned*)&prow[k] = pk;
    }
}

// ---------------------------------------------------------------------------
// Y = P @ V (LDS MFMA BK=64, split-K=4 -> 1024 blocks). bf16 partials.
// ---------------------------------------------------------------------------
__global__ __launch_bounds__(256) void k_pv_mfma(const u16* __restrict__ Pb,
                                                 const u16* __restrict__ Vt,
                                                 u16* __restrict__ Yp,
                                                 int L, int F, int ksplit)
{
    __shared__ u16 lAs[8192], lBs[8192];
    const int tid = threadIdx.x, wave = tid >> 6, lane = tid & 63;
    const int bi = blockIdx.z / ksplit, ks = blockIdx.z % ksplit;
    const int kf = L / ksplit;
    f32x4 acc[4][4];
#pragma unroll
    for (int i = 0; i < 4; ++i)
#pragma unroll
        for (int j = 0; j < 4; ++j) acc[i][j] = (f32x4){0.f, 0.f, 0.f, 0.f};
    mfma_nt(Pb + (size_t)bi * L * L + (size_t)blockIdx.y * 128 * L + (size_t)ks * kf, L,
            Vt + (size_t)bi * F * L + (size_t)blockIdx.x * 128 * L + (size_t)ks * kf, L,
            kf / 32, wave, lane, lAs, lBs, acc);
    const int wm = (wave >> 1) * 64, wn = (wave & 1) * 64;
    const int rb = (lane >> 4) * 4, cb = lane & 15;
    u16* Cp = Yp + ((size_t)(ks * Bb + bi) * L) * F;
#pragma unroll
    for (int i = 0; i < 4; ++i)
#pragma unroll
        for (int reg = 0; reg < 4; ++reg) {
            int gm = blockIdx.y * 128 + wm + i * 16 + rb + reg;
#pragma unroll
            for (int j = 0; j < 4; ++j) {
                int gn = blockIdx.x * 128 + wn + j * 16 + cb;
                Cp[(size_t)gm * F + gn] = f2bf(acc[i][j][reg]);
            }
        }
}

// ---------------------------------------------------------------------------
// Sum NSPLIT Yp partials + scatter to catbT[pix][cin].
// ---------------------------------------------------------------------------
template<int NSPLIT>
__global__ void k_unpatch(const u16* __restrict__ Yp, u16* __restrict__ catbT,
                          int ps, int outn, int L, int F, int cbase)
{
    size_t idx = (size_t)blockIdx.x * 256 + threadIdx.x;
    size_t total = (size_t)Bb * L * F / 4;
    if (idx >= total) return;
    const size_t pstr = (size_t)Bb * L * F;
    int f0 = (int)((idx * 4) % F);
    size_t t2 = (idx * 4) / F;
    int l = (int)(t2 % L);
    int bi = (int)(t2 / L);
    size_t off = ((size_t)bi * L + l) * F + f0;
    float s[4] = {0.f, 0.f, 0.f, 0.f};
#pragma unroll
    for (int sp = 0; sp < NSPLIT; ++sp) {
        uint2 u = *(const uint2*)&Yp[(size_t)sp * pstr + off];
        s[0] += bf2f((u16)(u.x & 0xffffu));
        s[1] += bf2f((u16)(u.x >> 16));
        s[2] += bf2f((u16)(u.y & 0xffffu));
        s[3] += bf2f((u16)(u.y >> 16));
    }
    int hw = ps * ps;
    int c = cbase + f0 / hw, r0 = f0 % hw;
    int ti = l / (outn * outn); int rem = l % (outn * outn);
    int oh = rem / outn, ow = rem % outn;
    int n = bi * Tt + ti;
    int py = r0 / ps, px = r0 % ps;   // r0 4-aligned -> same row, 4 consecutive px
    size_t base = ((size_t)n * PIX + (size_t)(oh * ps + py) * 64 + ow * ps + px) * Dc + c;
#pragma unroll
    for (int e = 0; e < 4; ++e)
        catbT[base + (size_t)e * Dc] = f2bf(s[e]);
}

// ---------------------------------------------------------------------------
// Output conv 3x3 as implicit NT GEMM over catbT, tap-split 2-way, BK=64
// pairing (2 (tap,kc) chunks per barrier; 9 pairs per split).
// grid (512, 2) = 1024 blocks. bf16 [pix][cout] partials.
// ---------------------------------------------------------------------------
__global__ __launch_bounds__(256) void k_conv_mfma(const u16* __restrict__ catbT,
                                                   const u16* __restrict__ WoT,
                                                   const u16* __restrict__ zp,
                                                   u16* __restrict__ Cpart)
{
    __shared__ u16 lAs[8192], lBs[8192];
    const int tid = threadIdx.x, wave = tid >> 6, lane = tid & 63;
    const int pix0 = blockIdx.x * 128;
    const int sp = blockIdx.y;
    const int r = lane >> 2;
    const int kq8 = ((lane & 3) ^ ((r >> 1) & 3)) * 8;   // swizzled source seg
    int yb[2], xb[2], nn[2];
#pragma unroll
    for (int s = 0; s < 2; ++s) {
        int pg = pix0 + wave * 32 + r + s * 16;
        nn[s] = pg >> 12; yb[s] = (pg >> 6) & 63; xb[s] = pg & 63;
    }
    const u16* gb_base = WoT + (size_t)(wave * 32 + r) * 128 + kq8;
    f32x4 acc[4][4];
#pragma unroll
    for (int i = 0; i < 4; ++i)
#pragma unroll
        for (int j = 0; j < 4; ++j) acc[i][j] = (f32x4){0.f, 0.f, 0.f, 0.f};
    for (int tp = 0; tp < 9; ++tp) {
        const int t0 = sp * 18 + tp * 2;
        __syncthreads();
#pragma unroll
        for (int h = 0; h < 2; ++h) {
            const int t = t0 + h;
            const int tap = t >> 2, kc = t & 3;
            const int dy = tap / 3 - 1, dx = tap % 3 - 1;
            const u16* ga[2];
#pragma unroll
            for (int s = 0; s < 2; ++s) {
                int y = yb[s] + dy, xx = xb[s] + dx;
                bool ok = ((unsigned)y < 64u) && ((unsigned)xx < 64u);
                ga[s] = ok ? catbT + (((size_t)(nn[s] << 12) + y * 64 + xx) << 7) + kq8 + kc * 32 : zp;
            }
            const u16* gb = gb_base + tap * 16384 + kc * 32;
            GLOAD16(ga[0], lAs + h * 4096 + wave * 1024);
            GLOAD16(ga[1], lAs + h * 4096 + wave * 1024 + 512);
            GLOAD16(gb, lBs + h * 4096 + wave * 1024);
            GLOAD16(gb + 2048, lBs + h * 4096 + wave * 1024 + 512);
        }
        __syncthreads();
        mfma_chunk(lAs, lBs, wave, lane, acc);
        mfma_chunk(lAs + 4096, lBs + 4096, wave, lane, acc);
    }
    const int wm = (wave >> 1) * 64, wn = (wave & 1) * 64;
    const int rb = (lane >> 4) * 4, cb = lane & 15;
    u16* Cp = Cpart + (size_t)sp * 8388608;
#pragma unroll
    for (int i = 0; i < 4; ++i)
#pragma unroll
        for (int reg = 0; reg < 4; ++reg) {
            int gm = pix0 + wm + i * 16 + rb + reg;          // global pixel
#pragma unroll
            for (int j = 0; j < 4; ++j) {
                int gn = wn + j * 16 + cb;                   // cout
                Cp[(size_t)gm * 128 + gn] = f2bf(acc[i][j][reg]);
            }
        }
}

// ---------------------------------------------------------------------------
// Conv finalize: out = leaky(sum of 2 bf16 partials + bias), NCHW fp32.
// ---------------------------------------------------------------------------
__global__ __launch_bounds__(256) void k_cfin(const u16* __restrict__ Cpart,
                                              const float* __restrict__ bo,
                                              float* __restrict__ outp)
{
    const int pg0 = blockIdx.x * 64;
    const int lane = threadIdx.x & 63, wv = threadIdx.x >> 6;
    const int pix = pg0 + lane;
    const int n = pix >> 12, p = pix & 4095;
    const u16* r0 = Cpart + (size_t)pix * 128 + wv * 32;
    const u16* r1 = r0 + 8388608;
#pragma unroll
    for (int c4 = 0; c4 < 8; ++c4) {
        uint2 a = *(const uint2*)(r0 + c4 * 4);
        uint2 b = *(const uint2*)(r1 + c4 * 4);
        float s[4];
        s[0] = bf2f((u16)(a.x & 0xffffu)) + bf2f((u16)(b.x & 0xffffu));
        s[1] = bf2f((u16)(a.x >> 16))     + bf2f((u16)(b.x >> 16));
        s[2] = bf2f((u16)(a.y & 0xffffu)) + bf2f((u16)(b.y & 0xffffu));
        s[3] = bf2f((u16)(a.y >> 16))     + bf2f((u16)(b.y >> 16));
#pragma unroll
        for (int e = 0; e < 4; ++e) {
            int cout = wv * 32 + c4 * 4 + e;
            float v = s[e] + bo[cout];
            v = (v >= 0.f) ? v : 0.2f * v;
            outp[((size_t)n * Dc + cout) * PIX + p] = v;
        }
    }
}

// ---------------------------------------------------------------------------
extern "C" void kernel_launch(void* const* d_in, const int* in_sizes, int n_in,
                              void* d_out, int out_size, void* d_ws, size_t ws_size,
                              hipStream_t stream)
{
    (void)in_sizes; (void)n_in; (void)out_size; (void)ws_size;
    const float* x    = (const float*)d_in[0];
    const float* mI   = (const float*)d_in[1];
    const float* dmap = (const float*)d_in[2];
    const float* wq   = (const float*)d_in[3];
    const float* bq   = (const float*)d_in[4];
    const float* wk   = (const float*)d_in[5];
    const float* bk   = (const float*)d_in[6];
    const float* wv   = (const float*)d_in[7];
    const float* bv   = (const float*)d_in[8];
    const float* wvle = (const float*)d_in[9];
    const float* bvle = (const float*)d_in[10];
    const float* wd1  = (const float*)d_in[11];
    const float* bd1  = (const float*)d_in[12];
    const float* wd2  = (const float*)d_in[13];
    const float* bd2  = (const float*)d_in[14];
    const float* wo   = (const float*)d_in[15];
    const float* bo   = (const float*)d_in[16];

    // workspace layout (~180 MB)
    char* w8 = (char*)d_ws;
    u16*   v_bf  = (u16*)(w8);                    // 16 MB
    u16*   Xt    = (u16*)(w8 + 0x1000000);        // 16 MB
    u16*   catbT = (u16*)(w8 + 0x2000000);        // 16 MB
    u16*   Qp0   = (u16*)(w8 + 0x3000000);        // 8 MB each (patched Q/K, both scales)
    u16*   Kp0   = (u16*)(w8 + 0x3800000);
    u16*   Qp1   = (u16*)(w8 + 0x4000000);
    u16*   Kp1   = (u16*)(w8 + 0x4800000);
    u16*   Vt    = (u16*)(w8 + 0x5000000);        // 8 MB
    u16*   Sb    = (u16*)(w8 + 0x5800000);        // 32 MB bf16 S partials
    u16*   Pb    = (u16*)(w8 + 0x7800000);        // 16 MB
    u16*   Yp    = (u16*)(w8 + 0x8800000);        // 32 MB pv partials
    u16*   Cpart = (u16*)(w8 + 0x5800000);        // conv partials: reuse Sb (dead after softmax i=1)
    // d1b (64 MB) ALIASES Qp0..Sb: depth path runs strictly before qkv/attn
    u16*   d1b   = (u16*)(w8 + 0x3000000);
    float* dep   = (float*)(w8 + 0xA800000);
    float* maskf = (float*)(w8 + 0xA840000);
    float* smed  = (float*)(w8 + 0xA844000);
    float* smaxA = (float*)(w8 + 0xA848000);
    float* sminA = (float*)(w8 + 0xA84C000);
    u16*   Wqkv  = (u16*)(w8 + 0xA850000);
    u16*   WoT   = (u16*)(w8 + 0xA868000);
    u16*   zp    = (u16*)(w8 + 0xA8B0000);
    float* part  = (float*)(w8 + 0xA8C0000);      // 2 MB
    float* outp  = (float*)d_out;

    hipMemcpyAsync(outp + 8388608, dmap, (size_t)16 * 65536 * sizeof(float),
                   hipMemcpyDeviceToDevice, stream);
    hipMemsetAsync(zp, 0, 256, stream);

    dim3 blk(256);
    // depth path first (d1b aliases Qp/Sb scratch)
    k_d1<<<dim3(32, 16), blk, 0, stream>>>(dmap, wd1, bd1, d1b);
    k_d2p<<<dim3(4, 16, 8), blk, 0, stream>>>(d1b, wd2, part);
    k_dfin<<<dim3(256), blk, 0, stream>>>(part, bd2, dep);

    k_prep<<<dim3(768), blk, 0, stream>>>(wq, wk, wv, wo, Wqkv, WoT);
    k_xt<<<dim3(64, 16), blk, 0, stream>>>(x, Xt);
    k_qkv_mfma<<<dim3(32, 3, 16), blk, 0, stream>>>(Wqkv, Xt, bq, bk, bv,
                                                    Qp0, Kp0, Qp1, Kp1, v_bf);
    k_vdw<<<dim3(128, 16), blk, 0, stream>>>(x, wvle, bvle, v_bf);

    for (int i = 0; i < 2; ++i) {
        const int ps = (i == 0) ? 4 : 8;
        const int outn = 64 / ps;
        const int L = Tt * outn * outn;        // 2048 / 512
        const int F = 64 * ps * ps;            // 1024 / 4096
        const int cbase = i * 64;
        const float scale = 1.0f / sqrtf((float)F);
        const int ksplit  = (i == 0) ? 2 : 16; // qkT grids: 1024 / 512 blocks
        const int pvsplit = 4;                 // pv grids: 1024 / 1024 blocks
        const u16* Qp = (i == 0) ? Qp0 : Qp1;
        const u16* Kp = (i == 0) ? Kp0 : Kp1;

        if (i == 0) k_stats2<4><<<dim3(Bb * L * 16 / 256), blk, 0, stream>>>(mI, dep, maskf, smed, smaxA, sminA, outn, L);
        else        k_stats2<8><<<dim3(Bb * L * 64 / 256), blk, 0, stream>>>(mI, dep, maskf, smed, smaxA, sminA, outn, L);

        const int pgrid = (int)(((size_t)Bb * L * F / 4 + 255) / 256);
        k_patchT<<<dim3(pgrid), blk, 0, stream>>>(v_bf, Vt, ps, outn, L, F, cbase);

        k_qkT_mfma<<<dim3(L / 128, L / 128, Bb * ksplit), blk, 0, stream>>>(Qp, Kp, Sb, L, F, ksplit, scale);

        if (i == 0) k_softmax<4, 2><<<dim3(L, Bb), blk, 0, stream>>>(Sb, Pb, maskf, smed, smaxA, sminA, L);
        else        k_softmax<1, 16><<<dim3(L, Bb), blk, 0, stream>>>(Sb, Pb, maskf, smed, smaxA, sminA, L);

        k_pv_mfma<<<dim3(F / 128, L / 128, Bb * pvsplit), blk, 0, stream>>>(Pb, Vt, Yp, L, F, pvsplit);
        k_unpatch<4><<<dim3(pgrid), blk, 0, stream>>>(Yp, catbT, ps, outn, L, F, cbase);
    }

    k_conv_mfma<<<dim3(512, 2), blk, 0, stream>>>(catbT, WoT, zp, Cpart);
    k_cfin<<<dim3(1024), blk, 0, stream>>>(Cpart, bo, outp);
}